// Round 8
// baseline (61.592 us; speedup 1.0000x reference)
//
#include <hip/hip_runtime.h>

#define HID   32
#define INCH  128
#define OUTD  8
#define BATCH 512
#define TLEN  512
#define TT    32
#define NCHUNK (TLEN / TT)

#define XSTRIDE 68   // padded dword stride per channel-pair row of the x tile

typedef __attribute__((ext_vector_type(2)))  float  f32x2;
typedef __attribute__((ext_vector_type(4)))  float  vf4;
typedef __attribute__((ext_vector_type(8)))  short  short8_t;
typedef __attribute__((ext_vector_type(16))) float  f32x16_t;
typedef __attribute__((ext_vector_type(2)))  int    i32x2;

#define ROR_CTRL(N) (0x120 | (N))

// DPP row_ror:N semantics (GCN/CDNA): dest lane i = src lane (i-N)&15 within
// each 16-lane row (data rotates toward higher lanes, like row_shr with wrap).
// Verified by the canonical DPP reduction (row_shr accumulates toward lane 63).
#define RORF(v, N) __int_as_float(__builtin_amdgcn_update_dpp(              \
    0, __float_as_int(v), ROR_CTRL(N), 0xF, 0xF, true))

// masked DPP update: 16-lane rows in rmask get ror:N of src, others keep old
#define UPDF(old, src, N, rmask) __int_as_float(__builtin_amdgcn_update_dpp(\
    __float_as_int(old), __float_as_int(src), ROR_CTRL(N), (rmask), 0xF, false))

// p_own + p[lane^32]  (verified functional-swap idiom, round 6)
__device__ __forceinline__ float swap32_add(float p)
{
#if __has_builtin(__builtin_amdgcn_permlane32_swap)
    i32x2 r = __builtin_amdgcn_permlane32_swap(
        __float_as_int(p), __float_as_int(p), false, false);
    return __int_as_float(r[0]) + __int_as_float(r[1]);
#else
    return p + __shfl_xor(p, 32, 64);
#endif
}

// p_own + p[lane^16]
__device__ __forceinline__ float swap16_add(float p)
{
#if __has_builtin(__builtin_amdgcn_permlane16_swap)
    i32x2 r = __builtin_amdgcn_permlane16_swap(
        __float_as_int(p), __float_as_int(p), false, false);
    return __int_as_float(r[0]) + __int_as_float(r[1]);
#else
    return p + __shfl_xor(p, 16, 64);
#endif
}

// Split fp32 -> bf16 hi (bit-truncate) + bf16 lo (truncated residual).
__device__ __forceinline__ void split8(const float4 f0, const float4 f1,
                                       short8_t* hi, short8_t* lo)
{
    float x[8] = {f0.x, f0.y, f0.z, f0.w, f1.x, f1.y, f1.z, f1.w};
    short8_t h, l;
    #pragma unroll
    for (int e = 0; e < 8; ++e) {
        const unsigned u  = __float_as_uint(x[e]);
        const unsigned hb = u & 0xFFFF0000u;
        h[e] = (short)(u >> 16);
        const float r = x[e] - __uint_as_float(hb);
        l[e] = (short)(__float_as_uint(r) >> 16);
    }
    *hi = h; *lo = l;
}

// ---------------------------------------------------------------------------
// One block per batch row; 2 waves.
//   wave 0 (scan): h = relu(x_t + W_hh h) with a DPP-ring matvec.
//     4 redundant 16-lane rows (g); lane (g,q) owns channels {2q,2q+1} and
//     holds the h-pair of position (q-4g)&15 (pre-rotated by row). Uniform
//     row_ror:s reads (s=0..3) + pk_fma cover j-pairs jp=(q-4g-s)&15, with
//     W_hh pre-permuted per lane to match. Combine rows via permlane16_swap
//     + permlane32_swap; redistribute h_next into pre-rotated form with two
//     masked update_dpp per reg (rows get ror 0/4/8/12). NO LDS on chain.
//   wave 1 (proj): split-bf16 MFMA 32x32x128 GEMM per chunk; D stored to a
//     padded channel-pair-major x tile ([pair][t] f32x2, stride 68 dwords).
// ---------------------------------------------------------------------------
__global__ __launch_bounds__(128, 1) void rnn_fused_kernel(
    const float* __restrict__ seq, const float* __restrict__ Wih,
    const float* __restrict__ Whh, const float* __restrict__ bih,
    const float* __restrict__ bhh, const float* __restrict__ Wfc,
    const float* __restrict__ bfc, float* __restrict__ out)
{
    __shared__ __align__(16) float xlds[2][16 * XSTRIDE];  // 8.7 KB dbuf
    __shared__ __align__(16) float hlds[HID];

    const int tid  = threadIdx.x;
    const int wid  = tid >> 6;
    const int l    = tid & 63;
    const int row  = blockIdx.x;

    if (wid == 0) {
        // ============================ SCAN ============================
        const int g = l >> 4;          // 16-lane row = rotation group
        const int q = l & 15;          // ring position; channels 2q, 2q+1

        // W_hh pairs, pre-permuted for (group, rotation) under the CORRECT
        // ror direction: w2[cc][s] = (W[2q+cc][2jp], W[2q+cc][2jp+1]),
        // jp = (q - 4g - s) & 15.
        f32x2 w2[2][4];
        #pragma unroll
        for (int cc = 0; cc < 2; ++cc)
            #pragma unroll
            for (int s = 0; s < 4; ++s) {
                const int jp = (q - 4 * g - s) & 15;
                w2[cc][s] = *(const f32x2*)(Whh + (2 * q + cc) * HID + 2 * jp);
            }

        float hA = 0.0f, hB = 0.0f;    // pre-rotated pair h[2p], h[2p+1]

        __builtin_amdgcn_s_setprio(1);
        for (int c = 0; c < NCHUNK; ++c) {
            __syncthreads();                           // chunk c published
            const float* xt = xlds[c & 1] + q * XSTRIDE;
            vf4 xq[16];                                // 32 steps of x pairs
            #pragma unroll
            for (int u = 0; u < 16; ++u) xq[u] = *(const vf4*)(xt + 4 * u);

            #pragma unroll
            for (int tt = 0; tt < TT; ++tt) {
                const float xv0 = (tt & 1) ? xq[tt >> 1].z : xq[tt >> 1].x;
                const float xv1 = (tt & 1) ? xq[tt >> 1].w : xq[tt >> 1].y;
                f32x2 h2; h2.x = hA; h2.y = hB;
                f32x2 a0 = w2[0][0] * h2;              // pk mul/fma
                f32x2 a1 = w2[1][0] * h2;
                f32x2 hs;
                hs.x = RORF(hA, 1); hs.y = RORF(hB, 1);
                a0 = w2[0][1] * hs + a0;  a1 = w2[1][1] * hs + a1;
                hs.x = RORF(hA, 2); hs.y = RORF(hB, 2);
                a0 = w2[0][2] * hs + a0;  a1 = w2[1][2] * hs + a1;
                hs.x = RORF(hA, 3); hs.y = RORF(hB, 3);
                a0 = w2[0][3] * hs + a0;  a1 = w2[1][3] * hs + a1;
                float p0 = a0.x + a0.y;
                float p1 = a1.x + a1.y;
                p0 = swap16_add(p0);  p1 = swap16_add(p1);   // row g + g^1
                p0 = swap32_add(p0);  p1 = swap32_add(p1);   // + g^2, g^3
                const float y0 = fmaxf(p0 + xv0, 0.0f);      // h_next[2q]
                const float y1 = fmaxf(p1 + xv1, 0.0f);      // h_next[2q+1]
                // redistribute into pre-rotated form (dest i = src (i-N)):
                // rows end with rotation 0 / 4 / 8 / 12
                const float tA = UPDF(y0, y0, 8, 0xC);
                hA = UPDF(tA, tA, 4, 0xA);
                const float tB = UPDF(y1, y1, 8, 0xC);
                hB = UPDF(tB, tB, 4, 0xA);
            }
        }
        __builtin_amdgcn_s_setprio(0);

        // FC head: row 0 lanes hold unrotated pairs -> stage h, then dot.
        if (g == 0) {
            f32x2 hp; hp.x = hA; hp.y = hB;
            *(f32x2*)&hlds[2 * q] = hp;
        }
        if (l < OUTD) {                 // same wave: LDS ops are in-order
            float s = bfc[l];
            #pragma unroll
            for (int j = 0; j < HID; ++j)
                s = fmaf(hlds[j], Wfc[l * HID + j], s);
            out[row * OUTD + l] = s;
        }
    } else {
        // ============================ PROJ ============================
        const int trow  = l & 31;          // timestep within chunk (A row)
        const int khalf = l >> 5;          // k-half selector
        const int irow  = l & 31;          // channel (B col / W_ih row)

        short8_t whi[8], wlo[8];
        #pragma unroll
        for (int kb = 0; kb < 8; ++kb) {
            const float* wp = Wih + irow * INCH + kb * 16 + khalf * 8;
            const float4 f0 = *(const float4*)(wp);
            const float4 f1 = *(const float4*)(wp + 4);
            split8(f0, f1, &whi[kb], &wlo[kb]);
        }
        const float biasv = bih[irow] + bhh[irow];

        for (int c = 0; c < NCHUNK; ++c) {
            const float* sp = seq +
                ((size_t)row * TLEN + (size_t)c * TT + trow) * INCH + khalf * 8;
            short8_t ahi[8], alo[8];
            #pragma unroll
            for (int kb = 0; kb < 8; ++kb) {
                const float4 f0 = *(const float4*)(sp + kb * 16);
                const float4 f1 = *(const float4*)(sp + kb * 16 + 4);
                split8(f0, f1, &ahi[kb], &alo[kb]);
            }

            f32x16_t acc;
            #pragma unroll
            for (int r2 = 0; r2 < 16; ++r2) acc[r2] = biasv;
            #pragma unroll
            for (int kb = 0; kb < 8; ++kb) {
                acc = __builtin_amdgcn_mfma_f32_32x32x16_bf16(ahi[kb], whi[kb], acc, 0, 0, 0);
                acc = __builtin_amdgcn_mfma_f32_32x32x16_bf16(ahi[kb], wlo[kb], acc, 0, 0, 0);
                acc = __builtin_amdgcn_mfma_f32_32x32x16_bf16(alo[kb], whi[kb], acc, 0, 0, 0);
            }

            // D row m = (r2&3)+8*(r2>>2)+4*khalf (timestep), col = irow.
            // Store into pair-tile: dword offset (irow>>1)*68 + 2m + (irow&1)
            float* xb = xlds[c & 1];
            #pragma unroll
            for (int r2 = 0; r2 < 16; ++r2) {
                const int m = (r2 & 3) + 8 * (r2 >> 2) + 4 * khalf;
                xb[(irow >> 1) * XSTRIDE + 2 * m + (irow & 1)] = acc[r2];
            }
            __syncthreads();                           // publish chunk c
        }
    }
}

extern "C" void kernel_launch(void* const* d_in, const int* in_sizes, int n_in,
                              void* d_out, int out_size, void* d_ws, size_t ws_size,
                              hipStream_t stream) {
    const float* seq = (const float*)d_in[0];
    const float* Wih = (const float*)d_in[1];
    const float* Whh = (const float*)d_in[2];
    const float* bih = (const float*)d_in[3];
    const float* bhh = (const float*)d_in[4];
    const float* Wfc = (const float*)d_in[5];
    const float* bfc = (const float*)d_in[6];

    rnn_fused_kernel<<<dim3(BATCH), dim3(128), 0, stream>>>(
        seq, Wih, Whh, bih, bhh, Wfc, bfc, (float*)d_out);
}